// Round 30
// baseline (85.151 us; speedup 1.0000x reference)
//
#include <hip/hip_runtime.h>
#include <hip/hip_bf16.h>

#define BATCH 256
#define L 1024
#define C 16
#define POOL 512
#define PCOLS 5632
#define FDIM 90112        // 11 levels * 8192
#define H1 128
#define H2 64

#define KS 256            // split-K factor for fc1 mfma GEMM
#define KCHUNK (FDIM / KS)   // 352

#define SROW 24                    // bf16 per state row (48B, 16B-aligned)
#define HROWS 513                  // 512 + zero row
#define HBUFS (HROWS * SROW)       // shorts per half-buffer
#define T8_LDS_BYTES (2 * HBUFS * 2 + 2047 * 4)   // 49248 + 8188 = 57436 -> 2 blocks/CU

typedef float f32x4 __attribute__((ext_vector_type(4)));
typedef short bf16x8 __attribute__((ext_vector_type(8)));
typedef unsigned long long u64;

__device__ __forceinline__ unsigned short f2b(float f) {
    union { __hip_bfloat16 h; unsigned short u; } cv;
    cv.h = __float2bfloat16(f);          // RNE, hardware v_cvt
    return cv.u;
}
__device__ __forceinline__ unsigned int pk(float lo, float hi) {
    return (unsigned int)f2b(lo) | ((unsigned int)f2b(hi) << 16);
}

// ---------------- Kernel 1a: tree levels leaf..8, half-batch blocks (2/CU) ---------
// grid 512 = (batch, half); halves independent through level 8 (nodes nest in 512).
// Transposed-D MFMA (R29), permute interleaved (R27), level-8 state -> glvl8.
__launch_bounds__(512, 4)
__global__ void tree08(const float* __restrict__ x,
                       const float* __restrict__ leaf_w,
                       const float* __restrict__ leaf_b,
                       const float* __restrict__ conv_w,
                       const float* __restrict__ conv_b,
                       const float* __restrict__ bn_gamma,
                       const float* __restrict__ bn_beta,
                       const float* __restrict__ node_w,
                       unsigned short* __restrict__ pooledb,
                       const float* __restrict__ w1,
                       unsigned short* __restrict__ w1p,
                       unsigned short* __restrict__ glvl8) {
    extern __shared__ short smem[];
    short* buf0 = smem;
    short* buf1 = smem + HBUFS;
    float* nwl  = (float*)(smem + 2 * HBUFS);   // node_w cache (2047 floats)

    const int bid = blockIdx.x;
    const int b   = bid >> 1;
    const int h   = bid & 1;
    const int tid = threadIdx.x;          // 0..511
    const int lane = tid & 63;
    const int wvv  = tid >> 6;            // 0..7
    const int n    = lane & 15;
    const int g    = lane >> 4;

    if (tid < SROW) {
        buf0[512 * SROW + tid] = 0;
        buf1[512 * SROW + tid] = 0;
    }
    for (int i = tid; i < 2047; i += 512) nwl[i] = node_w[i];

    bf16x8 A1, A2;
#pragma unroll
    for (int j = 0; j < 8; ++j) {
        const int ci = (g & 1) * 8 + j;
        A1[j] = (short)f2b(conv_w[(n * C + ci) * 3 + (g >> 1)]);
        A2[j] = (g < 2) ? (short)f2b(conv_w[(n * C + ci) * 3 + 2]) : (short)0;
    }
    const float scn = bn_gamma[n] / sqrtf(1.0f + 1e-5f);
    const float btn = conv_b[n] * scn + bn_beta[n];

    // ---- leaf stage: 1 global position per thread ----
    {
        const int gp = h * 512 + tid;
        const float xv = x[b * L + gp];
        const float nw = node_w[gp];
        const float4* lwa = (const float4*)(leaf_w + 16 * gp);
        const float4* lba = (const float4*)(leaf_b + 16 * gp);
        short* row = buf0 + tid * SROW;
#pragma unroll 1
        for (int q = 0; q < 4; ++q) {
            float4 wq = lwa[q], bq = lba[q];
            float v0 = (xv * wq.x + bq.x) * nw;
            float v1 = (xv * wq.y + bq.y) * nw;
            float v2 = (xv * wq.z + bq.z) * nw;
            float v3 = (xv * wq.w + bq.w) * nw;
            *(u64*)(row + 4 * q) =
                (u64)pk(v0, v1) | ((u64)pk(v2, v3) << 32);
            float p0 = fmaxf(v0, __shfl_xor(v0, 1));
            float p1 = fmaxf(v1, __shfl_xor(v1, 1));
            float p2 = fmaxf(v2, __shfl_xor(v2, 1));
            float p3 = fmaxf(v3, __shfl_xor(v3, 1));
            if (!(tid & 1)) {
                *(u64*)(pooledb + (long)b * FDIM + (gp >> 1) * 16 + 4 * q) =
                    (u64)pk(p0, p1) | ((u64)pk(p2, p3) << 32);
            }
        }
        __syncthreads();   // zero rows + nwl + leaf state visible
    }

    // ---- levels 0..8 via transposed MFMA ----
    short* bin  = buf0;
    short* bout = buf1;
    int noff = L;
    for (int d = 0; d < 9; ++d) {
        const int sh = d + 1;
        const int mask = (1 << sh) - 1;          // <= 511

        // --- permute round d (of 11) ---
        {
            const int gidx = (bid * 11 + d) * 512 + tid;
            const int pos2 = gidx & 511;
            const int c4   = (gidx >> 9) & 3;
            const int un   = gidx >> 11;          // 0..1407
            const int lev  = un >> 7;
            const int nr   = un & 127;
            const float* src = w1 + (long)nr * FDIM + lev * POOL + pos2;
            float f0 = src[(c4 * 4 + 0) * PCOLS];
            float f1 = src[(c4 * 4 + 1) * PCOLS];
            float f2 = src[(c4 * 4 + 2) * PCOLS];
            float f3 = src[(c4 * 4 + 3) * PCOLS];
            *(u64*)(w1p + (long)nr * FDIM + lev * 8192 + pos2 * 16 + c4 * 4) =
                (u64)pk(f0, f1) | ((u64)pk(f2, f3) << 32);
        }

        // --- phase 1: tap reads (local rows; masks valid since h*512 % L2 == 0) ---
        bf16x8 B1s[4], B2s[4];
#pragma unroll
        for (int ti = 0; ti < 4; ++ti) {
            const int lp = (wvv * 4 + ti) * 16 + n;
            const bool ok1 = (g >= 2) || ((lp & mask) != 0);
            const int r1 = ok1 ? (lp + (g >> 1) - 1) : 512;
            B1s[ti] = *(const bf16x8*)(bin + r1 * SROW + (g & 1) * 8);
            const bool ok2 = ((lp & mask) != mask);
            const int r2 = ok2 ? (lp + 1) : 512;
            B2s[ti] = *(const bf16x8*)(bin + r2 * SROW + (g & 1) * 8);
        }

        // --- phase 2: transposed MFMA + in-register pooling ---
#pragma unroll
        for (int ti = 0; ti < 4; ++ti) {
            const int base = (wvv * 4 + ti) * 16 + 4 * g;   // local; lane's 4 rows
            const int gb   = h * 512 + base;                // global position

            f32x4 acc = {0.f, 0.f, 0.f, 0.f};
            acc = __builtin_amdgcn_mfma_f32_16x16x32_bf16(B1s[ti], A1, acc, 0, 0, 0);
            acc = __builtin_amdgcn_mfma_f32_16x16x32_bf16(B2s[ti], A2, acc, 0, 0, 0);

            float z[4];
#pragma unroll
            for (int r = 0; r < 4; ++r) {
                const float nwv = nwl[noff + ((gb + r) >> sh)];
                z[r] = fmaxf(fmaf(scn, acc[r], btn), 0.f) * nwv;
            }

            if (d < 8) {
#pragma unroll
                for (int r = 0; r < 4; ++r)
                    bout[(base + r) * SROW + n] = (short)f2b(z[r]);
            } else {
                unsigned short* gp8 = glvl8 + ((long)b * L + gb) * 16 + n;
#pragma unroll
                for (int r = 0; r < 4; ++r)
                    gp8[r * 16] = f2b(z[r]);
            }

            const int pos2 = gb >> 1;
            unsigned short* pp = pooledb + (long)b * FDIM + sh * 8192 + pos2 * 16 + n;
            pp[0]  = f2b(fmaxf(z[0], z[1]));
            pp[16] = f2b(fmaxf(z[2], z[3]));
        }

        if (d >= 5 && d < 8) {
            __syncthreads();                 // next level reads cross-wave
        } else if (d < 8) {
            asm volatile("s_waitcnt lgkmcnt(0)" ::: "memory");
        }

        short* t = bin; bin = bout; bout = t;
        noff += (512 >> d);
    }

    // --- permute rounds 9, 10 ---
#pragma unroll
    for (int j = 9; j < 11; ++j) {
        const int gidx = (bid * 11 + j) * 512 + tid;
        const int pos2 = gidx & 511;
        const int c4   = (gidx >> 9) & 3;
        const int un   = gidx >> 11;
        const int lev  = un >> 7;
        const int nr   = un & 127;
        const float* src = w1 + (long)nr * FDIM + lev * POOL + pos2;
        float f0 = src[(c4 * 4 + 0) * PCOLS];
        float f1 = src[(c4 * 4 + 1) * PCOLS];
        float f2 = src[(c4 * 4 + 2) * PCOLS];
        float f3 = src[(c4 * 4 + 3) * PCOLS];
        *(u64*)(w1p + (long)nr * FDIM + lev * 8192 + pos2 * 16 + c4 * 4) =
            (u64)pk(f0, f1) | ((u64)pk(f2, f3) << 32);
    }
}

// ---------------- Kernel 1b: level 9 from glvl8 (global taps, no LDS/barriers) -----
__launch_bounds__(512, 4)
__global__ void tree9(const unsigned short* __restrict__ glvl8,
                      const float* __restrict__ conv_w,
                      const float* __restrict__ conv_b,
                      const float* __restrict__ bn_gamma,
                      const float* __restrict__ bn_beta,
                      const float* __restrict__ node_w,
                      unsigned short* __restrict__ pooledb) {
    const int b   = blockIdx.x;
    const int tid = threadIdx.x;
    const int lane = tid & 63;
    const int wvv  = tid >> 6;            // 0..7
    const int n    = lane & 15;
    const int g    = lane >> 4;

    bf16x8 A1, A2;
#pragma unroll
    for (int j = 0; j < 8; ++j) {
        const int ci = (g & 1) * 8 + j;
        A1[j] = (short)f2b(conv_w[(n * C + ci) * 3 + (g >> 1)]);
        A2[j] = (g < 2) ? (short)f2b(conv_w[(n * C + ci) * 3 + 2]) : (short)0;
    }
    const float scn = bn_gamma[n] / sqrtf(1.0f + 1e-5f);
    const float btn = conv_b[n] * scn + bn_beta[n];
    const float nwv = node_w[2046];       // single level-9 node

    const unsigned short* base8 = glvl8 + (long)b * L * 16;
    const bf16x8 zero = {0, 0, 0, 0, 0, 0, 0, 0};

#pragma unroll 1
    for (int ti = 0; ti < 8; ++ti) {
        const int pos = (wvv * 8 + ti) * 16 + n;
        const bool ok1 = (g >= 2) || (pos != 0);
        const int r1 = pos + (g >> 1) - 1;
        bf16x8 B1 = ok1 ? *(const bf16x8*)(base8 + (long)r1 * 16 + (g & 1) * 8) : zero;
        const bool ok2 = (pos != L - 1);
        bf16x8 B2 = ok2 ? *(const bf16x8*)(base8 + (long)(pos + 1) * 16 + (g & 1) * 8) : zero;

        f32x4 acc = {0.f, 0.f, 0.f, 0.f};
        acc = __builtin_amdgcn_mfma_f32_16x16x32_bf16(B1, A1, acc, 0, 0, 0);
        acc = __builtin_amdgcn_mfma_f32_16x16x32_bf16(B2, A2, acc, 0, 0, 0);

        const int cb = (wvv * 8 + ti) * 16 + 4 * g;   // lane's 4 output rows
        float z[4];
#pragma unroll
        for (int r = 0; r < 4; ++r)
            z[r] = fmaxf(fmaf(scn, acc[r], btn), 0.f) * nwv;

        const int pos2 = cb >> 1;
        unsigned short* pp = pooledb + (long)b * FDIM + 10 * 8192 + pos2 * 16 + n;
        pp[0]  = f2b(fmaxf(z[0], z[1]));
        pp[16] = f2b(fmaxf(z[2], z[3]));
    }
}

// ---------------- Kernel 2: fc1 via MFMA, full 256x128/block, BF16 partials --------
__launch_bounds__(512, 2)
__global__ void fc1_mfma(const unsigned short* __restrict__ pooledb,
                         const unsigned short* __restrict__ w1b,
                         unsigned int* __restrict__ p32) {
    const int ks  = blockIdx.x;          // 0..255

    const int tid  = threadIdx.x;
    const int wv   = tid >> 6;           // 0..7
    const int lane = tid & 63;
    const int lrow = lane & 15;
    const int lk   = (lane >> 4) * 8;

    const int m0 = wv * 32;
    const int kb = ks * KCHUNK;

    const unsigned short* ap0 = pooledb + (long)(m0 + lrow) * FDIM + kb + lk;
    const unsigned short* ap1 = ap0 + (long)16 * FDIM;
    const unsigned short* bp  = w1b + (long)lrow * FDIM + kb + lk;

    f32x4 acc[2][8];
#pragma unroll
    for (int i = 0; i < 2; ++i)
#pragma unroll
        for (int ct = 0; ct < 8; ++ct) acc[i][ct] = (f32x4){0.f, 0.f, 0.f, 0.f};

#pragma unroll 1
    for (int kk = 0; kk < KCHUNK; kk += 32) {
        bf16x8 a0 = *(const bf16x8*)(ap0 + kk);
        bf16x8 a1 = *(const bf16x8*)(ap1 + kk);
#pragma unroll
        for (int ct = 0; ct < 8; ++ct) {
            bf16x8 bv = *(const bf16x8*)(bp + (long)(ct * 16) * FDIM + kk);
            acc[0][ct] = __builtin_amdgcn_mfma_f32_16x16x32_bf16(a0, bv, acc[0][ct], 0, 0, 0);
            acc[1][ct] = __builtin_amdgcn_mfma_f32_16x16x32_bf16(a1, bv, acc[1][ct], 0, 0, 0);
        }
    }

    const int rbase = (lane >> 4) * 4;
    const int half  = lane & 1;
    const int cpair = (lane & 15) >> 1;
#pragma unroll
    for (int r = 0; r < 4; ++r) {
        const int row = m0 + (half << 4) + rbase + r;
        unsigned int* p = p32 + (long)row * (KS * 64) + ks * 64 + cpair;
#pragma unroll
        for (int ct = 0; ct < 8; ++ct) {
            float x0 = acc[0][ct][r], x1 = acc[1][ct][r];
            float y0 = __shfl_xor(x0, 1), y1 = __shfl_xor(x1, 1);
            float lo = half ? y1 : x0;
            float hi = half ? x1 : y0;
            p[ct * 8] = pk(lo, hi);
        }
    }
}

// ---------------- Kernel 3: bf16 partial-reduce + fc1 bias/relu + fc2 + fc3 -------
__launch_bounds__(1024)
__global__ void fc_tail(const unsigned int* __restrict__ p32,
                        const float* __restrict__ fc1_b,
                        const float* __restrict__ w2,
                        const float* __restrict__ b2,
                        const float* __restrict__ w3,
                        const float* __restrict__ b3,
                        float* __restrict__ out) {
    __shared__ float red[16][H1];
    __shared__ float h1_s[H1];
    __shared__ float w2_s[H2 * 129];

    const int b = blockIdx.x;
    const int tid = threadIdx.x;
    const int t2 = tid & 63;
    const int q  = tid >> 6;

    float s0 = 0.f, s1 = 0.f;
    const unsigned int* pb = p32 + (long)b * (KS * 64) + (q * 16) * 64 + t2;
#pragma unroll
    for (int kt = 0; kt < 16; ++kt) {
        unsigned int v = pb[kt * 64];
        union { unsigned int u; float f; } lo, hi;
        lo.u = v << 16;
        hi.u = v & 0xffff0000u;
        s0 += lo.f;
        s1 += hi.f;
    }
    red[q][2 * t2]     = s0;
    red[q][2 * t2 + 1] = s1;

    for (int i = tid; i < H2 * H1; i += 1024) {
        int j = i >> 7, k = i & 127;
        w2_s[j * 129 + k] = w2[i];
    }
    __syncthreads();

    if (tid < 128) {
        float ss = 0.f;
#pragma unroll
        for (int qq = 0; qq < 16; ++qq) ss += red[qq][tid];
        h1_s[tid] = fmaxf(ss + fc1_b[tid], 0.f);
    }
    __syncthreads();

    if (tid < 64) {
        float a2 = 0.f;
#pragma unroll 8
        for (int k = 0; k < H1; ++k) a2 = fmaf(h1_s[k], w2_s[tid * 129 + k], a2);
        float h2 = fmaxf(a2 + b2[tid], 0.f);
        float r = h2 * w3[tid];
#pragma unroll
        for (int off = 32; off > 0; off >>= 1) r += __shfl_down(r, off);
        if (tid == 0) out[b] = r + b3[0];
    }
}

extern "C" void kernel_launch(void* const* d_in, const int* in_sizes, int n_in,
                              void* d_out, int out_size, void* d_ws, size_t ws_size,
                              hipStream_t stream) {
    const float* x        = (const float*)d_in[0];
    const float* leaf_w   = (const float*)d_in[1];
    const float* leaf_b   = (const float*)d_in[2];
    const float* conv_w   = (const float*)d_in[3];
    const float* conv_b   = (const float*)d_in[4];
    const float* bn_gamma = (const float*)d_in[5];
    const float* bn_beta  = (const float*)d_in[6];
    const float* node_w   = (const float*)d_in[7];
    const float* fc1_w    = (const float*)d_in[8];
    const float* fc1_b    = (const float*)d_in[9];
    const float* fc2_w    = (const float*)d_in[10];
    const float* fc2_b    = (const float*)d_in[11];
    const float* fc3_w    = (const float*)d_in[12];
    const float* fc3_b    = (const float*)d_in[13];

    // ws: pooled bf16 46.1 | w1p bf16 23.1 | p32 16.8 | glvl8 bf16 8.4 = 94.4 MB
    unsigned short* pooledb = (unsigned short*)d_ws;
    unsigned short* w1p     = pooledb + (long)BATCH * FDIM;
    unsigned int*   p32     = (unsigned int*)(w1p + (long)H1 * FDIM);
    unsigned short* glvl8   = (unsigned short*)(p32 + (long)BATCH * KS * 64);

    (void)hipFuncSetAttribute((const void*)tree08,
                        hipFuncAttributeMaxDynamicSharedMemorySize, T8_LDS_BYTES);

    tree08<<<BATCH * 2, 512, T8_LDS_BYTES, stream>>>(
        x, leaf_w, leaf_b, conv_w, conv_b, bn_gamma, bn_beta, node_w, pooledb,
        fc1_w, w1p, glvl8);

    tree9<<<BATCH, 512, 0, stream>>>(glvl8, conv_w, conv_b, bn_gamma, bn_beta,
                                     node_w, pooledb);

    fc1_mfma<<<KS, 512, 0, stream>>>(pooledb, w1p, p32);

    fc_tail<<<BATCH, 1024, 0, stream>>>(p32, fc1_b, fc2_w, fc2_b, fc3_w, fc3_b,
                                        (float*)d_out);
}